// Round 15
// baseline (5651.786 us; speedup 1.0000x reference)
//
#include <hip/hip_runtime.h>
#include <stdint.h>
#include <stddef.h>

typedef uint32_t u32;
typedef float v2f __attribute__((ext_vector_type(2)));

// ---------------- problem constants (fixed by reference file) ----------------
#define NB    256      // batch B
#define LFULL 412      // L
#define NCH   3        // C
#define CTX   336      // context_length
#define NSAMP 100      // n_samples
#define TM1   383      // T-1 (T = L - MAX_LAG = 384)
#define HID   64
#define NIN   15
#define RTOT  25600    // NB*NSAMP
#define NCTXS 8601600u // RTOT*CTX
#define NSTEP 47       // H-1

#define DROWS   8      // rows per persistent decode block (2 per wave)
#define DBLOCKS (RTOT / DROWS)  // 3200

#define JAX_PARTITIONABLE 1

__device__ const int c_LAGS[10] = {1,2,3,4,5,6,7,14,21,28};

__device__ inline v2f bc2(float x) { v2f r; r[0] = x; r[1] = x; return r; }

// ---------------- threefry2x32 (matches jax._src.prng) ----------------
__host__ __device__ inline void tf2x32(u32 k0, u32 k1, u32 x0, u32 x1, u32& o0, u32& o1) {
  const u32 ks2 = k0 ^ k1 ^ 0x1BD11BDAu;
#define TFR(r) { x0 += x1; x1 = (x1 << (r)) | (x1 >> (32 - (r))); x1 ^= x0; }
  x0 += k0; x1 += k1;
  TFR(13) TFR(15) TFR(26) TFR(6)
  x0 += k1; x1 += ks2 + 1u;
  TFR(17) TFR(29) TFR(16) TFR(24)
  x0 += ks2; x1 += k0 + 2u;
  TFR(13) TFR(15) TFR(26) TFR(6)
  x0 += k0; x1 += k1 + 3u;
  TFR(17) TFR(29) TFR(16) TFR(24)
  x0 += k1; x1 += ks2 + 4u;
  TFR(13) TFR(15) TFR(26) TFR(6)
  x0 += ks2; x1 += k0 + 5u;
#undef TFR
  o0 = x0; o1 = x1;
}

__host__ __device__ inline u32 split_word_legacy(u32 k0, u32 k1, u32 n, u32 j) {
  u32 o0, o1;
  if (j < n) { tf2x32(k0, k1, j, n + j, o0, o1); return o0; }
  tf2x32(k0, k1, j - n, j, o0, o1); return o1;
}

__host__ __device__ inline void jx_subkey(u32 k0, u32 k1, u32 n, u32 i, u32& s0, u32& s1) {
#if JAX_PARTITIONABLE
  (void)n; tf2x32(k0, k1, 0u, i, s0, s1);
#else
  s0 = split_word_legacy(k0, k1, n, 2u * i);
  s1 = split_word_legacy(k0, k1, n, 2u * i + 1u);
#endif
}

__device__ inline u32 jx_bits(u32 k0, u32 k1, u32 n, u32 i) {
#if JAX_PARTITIONABLE
  (void)n; u32 o0, o1; tf2x32(k0, k1, 0u, i, o0, o1); return o0 ^ o1;
#else
  u32 o0, o1;
  if (n == 1u) { tf2x32(k0, k1, 0u, 0u, o0, o1); return o0; }
  const u32 h = n >> 1;
  if (i < h) { tf2x32(k0, k1, i, h + i, o0, o1); return o0; }
  tf2x32(k0, k1, i - h, i, o0, o1); return o1;
#endif
}

// ---------------- JAX-exact float transforms ----------------
__device__ inline float jax_erfinv(float x) {
#pragma clang fp contract(off)
  float w = -log1pf(-x * x);
  float p;
  if (w < 5.0f) {
    w = w - 2.5f;
    p = 2.81022636e-08f;
    p = 3.43273939e-07f + p * w;
    p = -3.5233877e-06f + p * w;
    p = -4.39150654e-06f + p * w;
    p = 0.00021858087f + p * w;
    p = -0.00125372503f + p * w;
    p = -0.00417768164f + p * w;
    p = 0.246640727f + p * w;
    p = 1.50140941f + p * w;
  } else {
    w = sqrtf(w) - 3.0f;
    p = -0.000200214257f;
    p = 0.000100950558f + p * w;
    p = 0.00134934322f + p * w;
    p = -0.00367342844f + p * w;
    p = 0.00573950773f + p * w;
    p = -0.0076224613f + p * w;
    p = 0.00943887047f + p * w;
    p = 1.00167406f + p * w;
    p = 2.83297682f + p * w;
  }
  return p * x;
}

__device__ inline float u01_from_bits(u32 bits) {
  return __uint_as_float((bits >> 9) | 0x3f800000u) - 1.0f;
}

__device__ inline float normal_from_bits(u32 bits) {
#pragma clang fp contract(off)
  const float lo = -0.99999994f;
  const float u = u01_from_bits(bits);
  float r = u * 2.0f + lo;
  r = fmaxf(lo, r);
  return 1.41421356f * jax_erfinv(r);
}

__device__ float jax_gamma_one(u32 k0, u32 k1, float alpha) {
#pragma clang fp contract(off)
  const bool boost_mask = (alpha >= 1.0f);
  const float alpha_orig = alpha;
  const float a = boost_mask ? alpha : (alpha + 1.0f);
  const float d = a - 0.33333334f;
  const float c = 0.33333334f / sqrtf(d);
  u32 K0, K1, S0, S1;
  jx_subkey(k0, k1, 2u, 0u, K0, K1);
  jx_subkey(k0, k1, 2u, 1u, S0, S1);
  float u_boost = 1.0f;
  if (!boost_mask) u_boost = u01_from_bits(jx_bits(S0, S1, 1u, 0u));
  float X = 0.0f, V = 1.0f, U = 2.0f;
  while (true) {
    if (!(U >= 1.0f - 0.0331f * (X * X))) break;
    if (!(logf(U) >= 0.5f * X + d * ((1.0f - V) + logf(V)))) break;
    u32 nk0, nk1, xk0, xk1, uk0, uk1;
    jx_subkey(K0, K1, 3u, 0u, nk0, nk1);
    jx_subkey(K0, K1, 3u, 1u, xk0, xk1);
    jx_subkey(K0, K1, 3u, 2u, uk0, uk1);
    K0 = nk0; K1 = nk1;
    float x, v;
    u32 c0 = xk0, c1 = xk1;
    do {
      u32 t0, t1, s0, s1;
      jx_subkey(c0, c1, 2u, 0u, t0, t1);
      jx_subkey(c0, c1, 2u, 1u, s0, s1);
      c0 = t0; c1 = t1;
      x = normal_from_bits(jx_bits(s0, s1, 1u, 0u));
      v = 1.0f + x * c;
    } while (v <= 0.0f);
    X = x * x;
    V = (v * v) * v;
    U = u01_from_bits(jx_bits(uk0, uk1, 1u, 0u));
  }
  const float sample = d * V;
  const float boost = boost_mask ? 1.0f : powf(u_boost, 1.0f / alpha_orig);
  return sample * boost;
}

__device__ inline float sigm(float x) { return 1.0f / (1.0f + expf(-x)); }
__device__ inline float softplusf(float x) { return fmaxf(x, 0.0f) + log1pf(expf(-fabsf(x))); }

// cross-lane broadcast on the VALU pipe (not DS): v_readlane -> SGPR
__device__ inline float rl_f(float v, int l) {
  return __int_as_float(__builtin_amdgcn_readlane(__float_as_int(v), l));
}

// ---------------- workspace layout (floats) ----------------
enum : size_t {
  OFF_INP  = 0,
  OFF_CT   = OFF_INP + (size_t)NB * TM1 * NIN,
  OFF_TS   = OFF_CT + (size_t)NB * CTX,
  OFF_LTS  = OFF_TS + NB,
  OFF_DF   = OFF_LTS + NB,
  OFF_LOC  = OFF_DF + (size_t)NB * CTX,
  OFF_SC   = OFF_LOC + (size_t)NB * CTX,
  OFF_H0F  = OFF_SC + (size_t)NB * CTX,
  OFF_C0F  = OFF_H0F + (size_t)NB * HID,
  OFF_H1F  = OFF_C0F + (size_t)NB * HID,
  OFF_C1F  = OFF_H1F + (size_t)NB * HID,
  OFF_YH   = OFF_C1F + (size_t)NB * HID,
  OFF_WTX  = OFF_YH + (size_t)RTOT * TM1,     // Wih0^T padded [16][256]
  OFF_WT00 = OFF_WTX + 4096,                  // Whh0^T [64][256]
  OFF_WT10 = OFF_WT00 + 16384,                // Wih1^T [64][256]
  OFF_WT11 = OFF_WT10 + 16384,                // Whh1^T [64][256]
  OFF_RND  = OFF_WT11 + 16384,                // decode randoms [NSTEP][RTOT][4]
  WS_FLOATS = OFF_RND + (size_t)NSTEP * RTOT * 4   // ~16.6M floats ~66 MB
};

// ---------------- kernel 0a: transpose weights to [k][gate] ------------------
__global__ void __launch_bounds__(256) wtrans_kernel(
    const float* __restrict__ Wih0, const float* __restrict__ Whh0,
    const float* __restrict__ Wih1, const float* __restrict__ Whh1,
    float* __restrict__ WTx, float* __restrict__ WT00,
    float* __restrict__ WT10, float* __restrict__ WT11)
{
  const int i = blockIdx.x * 256 + threadIdx.x;   // < 53248
  if (i < 4096) {
    const int k = i >> 8, g = i & 255;
    WTx[i] = (k < 15) ? Wih0[g * 15 + k] : 0.0f;
  } else if (i < 4096 + 16384) {
    const int j = i - 4096, k = j >> 8, g = j & 255;
    WT00[j] = Whh0[g * 64 + k];
  } else if (i < 4096 + 32768) {
    const int j = i - 4096 - 16384, k = j >> 8, g = j & 255;
    WT10[j] = Wih1[g * 64 + k];
  } else {
    const int j = i - 4096 - 32768, k = j >> 8, g = j & 255;
    WT11[j] = Whh1[g * 64 + k];
  }
}

// ---------------- kernel 0b: precompute decode randoms -----------------------
__global__ void __launch_bounds__(256) rnd_dec_kernel(
    float* __restrict__ RND, u32 kl0, u32 kl1)
{
  const int i = blockIdx.x * 256 + threadIdx.x;   // < NSTEP*RTOT = 1203200
  const int s = i / RTOT, rg = i - s * RTOT;
  u32 ks0, ks1, skz0, skz1, skg0, skg1;
  tf2x32(kl0, kl1, 0u, (u32)s, ks0, ks1);
  tf2x32(ks0, ks1, 0u, 0u, skz0, skz1);
  tf2x32(ks0, ks1, 0u, 1u, skg0, skg1);
  const float z = normal_from_bits(jx_bits(skz0, skz1, RTOT, (u32)rg));
  u32 gk0, gk1;
  jx_subkey(skg0, skg1, RTOT, (u32)rg, gk0, gk1);
  u32 K0, K1, S0, S1;
  jx_subkey(gk0, gk1, 2u, 0u, K0, K1);
  jx_subkey(gk0, gk1, 2u, 1u, S0, S1);   // boost key, unused (alpha >= 1)
  u32 nk0, nk1, xk0, xk1, uk0, uk1;
  jx_subkey(K0, K1, 3u, 0u, nk0, nk1);
  jx_subkey(K0, K1, 3u, 1u, xk0, xk1);
  jx_subkey(K0, K1, 3u, 2u, uk0, uk1);
  u32 c0 = xk0, c1 = xk1, t0, t1, s0, s1;
  jx_subkey(c0, c1, 2u, 0u, t0, t1);
  jx_subkey(c0, c1, 2u, 1u, s0, s1);
  const float x1 = normal_from_bits(jx_bits(s0, s1, 1u, 0u));
  c0 = t0; c1 = t1;
  jx_subkey(c0, c1, 2u, 0u, t0, t1);
  jx_subkey(c0, c1, 2u, 1u, s0, s1);
  const float x2 = normal_from_bits(jx_bits(s0, s1, 1u, 0u));
  const float U1 = u01_from_bits(jx_bits(uk0, uk1, 1u, 0u));
  float* R = RND + (size_t)i * 4;
  R[0] = z; R[1] = x1; R[2] = x2; R[3] = U1;
}

// ---------------- kernel 1: tscale + feature build ----------------
__global__ void __launch_bounds__(256) prep_kernel(
    const float* __restrict__ X, const float* __restrict__ emb,
    float* __restrict__ inp, float* __restrict__ ct,
    float* __restrict__ tscale, float* __restrict__ ltscale)
{
  const int b = blockIdx.x, t = threadIdx.x;
  __shared__ float red[256];
  __shared__ float ts_sh;
  const float* Xb = X + (size_t)b * LFULL * NCH;
  float p = fabsf(Xb[(28 + t) * NCH]);
  if (t < 80) p += fabsf(Xb[(28 + 256 + t) * NCH]);
  red[t] = p;
  for (int st = 128; st > 0; st >>= 1) { __syncthreads(); if (t < st) red[t] += red[t + st]; }
  __syncthreads();
  if (t == 0) {
    float ts = red[0] / 336.0f;
    ts = fmaxf(ts, 1e-10f);
    tscale[b] = ts; ltscale[b] = logf(ts); ts_sh = ts;
  }
  __syncthreads();
  const float ts = ts_sh;
  const float lts = logf(ts);
  const float ev = emb[0];
  for (int idx = t; idx < TM1 * NIN; idx += 256) {
    const int tt = idx / NIN, f = idx - tt * NIN;
    float val;
    if (f == 0)       val = (tt < CTX) ? Xb[(28 + tt) * NCH] / ts : 0.0f;
    else if (f <= 10) val = (tt < CTX) ? Xb[(28 + tt - c_LAGS[f - 1]) * NCH] / ts : 0.0f;
    else if (f == 11) val = ev;
    else if (f == 12) val = Xb[(28 + tt) * NCH + 2];
    else if (f == 13) val = lts;
    else              val = Xb[(28 + tt) * NCH + 1];
    inp[(size_t)(b * TM1 + tt) * NIN + f] = val;
    if (f == 0 && tt < CTX) ct[b * CTX + tt] = val;
  }
}

// ---------------- kernel 2: context LSTM, dec-style streaming (R14, kept) ---
__global__ void __launch_bounds__(256) ctx_lstm_kernel(
    const float* __restrict__ inp,
    const float* __restrict__ WTx, const float* __restrict__ WT00,
    const float* __restrict__ WT10, const float* __restrict__ WT11,
    const float* __restrict__ bih0, const float* __restrict__ bhh0,
    const float* __restrict__ bih1, const float* __restrict__ bhh1,
    const float* __restrict__ wdf, const float* __restrict__ bdfp,
    const float* __restrict__ wloc, const float* __restrict__ blocp,
    const float* __restrict__ wsc, const float* __restrict__ bscp,
    float* __restrict__ dfo, float* __restrict__ loco, float* __restrict__ sco,
    float* __restrict__ h0f, float* __restrict__ c0f,
    float* __restrict__ h1f, float* __restrict__ c1f)
{
  const int b = blockIdx.x, t = threadIdx.x;
  const int lane = t & 63, w = t >> 6;
  const int gbase = lane << 2;
  __shared__ __align__(16) float gA[4][256];
  __shared__ __align__(16) float gB[4][256];

  const float bs0 = bih0[lane]       + bhh0[lane];
  const float bs1 = bih0[64 + lane]  + bhh0[64 + lane];
  const float bs2 = bih0[128 + lane] + bhh0[128 + lane];
  const float bs3 = bih0[192 + lane] + bhh0[192 + lane];
  const float bs4 = bih1[lane]       + bhh1[lane];
  const float bs5 = bih1[64 + lane]  + bhh1[64 + lane];
  const float bs6 = bih1[128 + lane] + bhh1[128 + lane];
  const float bs7 = bih1[192 + lane] + bhh1[192 + lane];
  const float wdfv = wdf[lane], wlocv = wloc[lane], wscv = wsc[lane];
  const float bdf = bdfp[0], bloc = blocp[0], bsc = bscp[0];

  float h0r = 0.f, h1r = 0.f, c0r = 0.f, c1r = 0.f;
  const float* inb = inp + (size_t)b * TM1 * NIN;
  const int kx = w * 4;    // x-part k-quarter
  const int kh = w * 16;   // h-part k-quarter

  for (int tt = 0; tt < CTX; tt++) {
    float xr = 0.f;
    if (lane < 15) xr = inb[tt * NIN + lane];

    v2f aA = bc2(0.0f), aB = bc2(0.0f);
#pragma unroll
    for (int kk = 0; kk < 4; kk++) {
      const int k = kx + kk;
      const float4 wv = *(const float4*)&WTx[(k << 8) + gbase];
      v2f wlo, whi; wlo[0] = wv.x; wlo[1] = wv.y; whi[0] = wv.z; whi[1] = wv.w;
      const v2f hk = bc2(rl_f(xr, k));
      aA += wlo * hk; aB += whi * hk;
    }
#pragma unroll
    for (int kk = 0; kk < 16; kk++) {
      const int k = kh + kk;
      const float4 wv = *(const float4*)&WT00[(k << 8) + gbase];
      v2f wlo, whi; wlo[0] = wv.x; wlo[1] = wv.y; whi[0] = wv.z; whi[1] = wv.w;
      const v2f hk = bc2(rl_f(h0r, k));
      aA += wlo * hk; aB += whi * hk;
    }
    {
      float4 gv; gv.x = aA[0]; gv.y = aA[1]; gv.z = aB[0]; gv.w = aB[1];
      *(float4*)&gA[w][gbase] = gv;
    }
    __syncthreads();

    {
      float gi = ((gA[0][lane]       + gA[1][lane])       + gA[2][lane])       + gA[3][lane];
      float gf = ((gA[0][64 + lane]  + gA[1][64 + lane])  + gA[2][64 + lane])  + gA[3][64 + lane];
      float gg = ((gA[0][128 + lane] + gA[1][128 + lane]) + gA[2][128 + lane]) + gA[3][128 + lane];
      float go = ((gA[0][192 + lane] + gA[1][192 + lane]) + gA[2][192 + lane]) + gA[3][192 + lane];
      gi += bs0; gf += bs1; gg += bs2; go += bs3;
      c0r = sigm(gf) * c0r + sigm(gi) * tanhf(gg);
      h0r = sigm(go) * tanhf(c0r);
    }

    aA = bc2(0.0f); aB = bc2(0.0f);
#pragma unroll
    for (int kk = 0; kk < 16; kk++) {
      const int k = kh + kk;
      const float4 wv = *(const float4*)&WT10[(k << 8) + gbase];
      v2f wlo, whi; wlo[0] = wv.x; wlo[1] = wv.y; whi[0] = wv.z; whi[1] = wv.w;
      const v2f hk = bc2(rl_f(h0r, k));
      aA += wlo * hk; aB += whi * hk;
    }
#pragma unroll
    for (int kk = 0; kk < 16; kk++) {
      const int k = kh + kk;
      const float4 wv = *(const float4*)&WT11[(k << 8) + gbase];
      v2f wlo, whi; wlo[0] = wv.x; wlo[1] = wv.y; whi[0] = wv.z; whi[1] = wv.w;
      const v2f hk = bc2(rl_f(h1r, k));
      aA += wlo * hk; aB += whi * hk;
    }
    {
      float4 gv; gv.x = aA[0]; gv.y = aA[1]; gv.z = aB[0]; gv.w = aB[1];
      *(float4*)&gB[w][gbase] = gv;
    }
    __syncthreads();

    {
      float gi = ((gB[0][lane]       + gB[1][lane])       + gB[2][lane])       + gB[3][lane];
      float gf = ((gB[0][64 + lane]  + gB[1][64 + lane])  + gB[2][64 + lane])  + gB[3][64 + lane];
      float gg = ((gB[0][128 + lane] + gB[1][128 + lane]) + gB[2][128 + lane]) + gB[3][128 + lane];
      float go = ((gB[0][192 + lane] + gB[1][192 + lane]) + gB[2][192 + lane]) + gB[3][192 + lane];
      gi += bs4; gf += bs5; gg += bs6; go += bs7;
      c1r = sigm(gf) * c1r + sigm(gi) * tanhf(gg);
      h1r = sigm(go) * tanhf(c1r);
      if (w == 0) {
        float pd = h1r * wdfv, pl = h1r * wlocv, ps = h1r * wscv;
#pragma unroll
        for (int off = 32; off > 0; off >>= 1) {
          pd += __shfl_down(pd, off, 64);
          pl += __shfl_down(pl, off, 64);
          ps += __shfl_down(ps, off, 64);
        }
        if (lane == 0) {
          dfo[b * CTX + tt]  = 2.0f + softplusf(pd + bdf);
          loco[b * CTX + tt] = pl + bloc;
          sco[b * CTX + tt]  = softplusf(ps + bsc);
        }
      }
    }
  }
  if (w == 0) {
    h0f[b * 64 + lane] = h0r; c0f[b * 64 + lane] = c0r;
    h1f[b * 64 + lane] = h1r; c1f[b * 64 + lane] = c1r;
  }
}

// ---------------- kernel 3: context sampling (y_ctx) ----------------
__global__ void __launch_bounds__(256) ctx_sample_kernel(
    const float* __restrict__ df, const float* __restrict__ loc, const float* __restrict__ sc,
    const float* __restrict__ tscale, float* __restrict__ yhat,
    u32 kz0, u32 kz1, u32 kg0, u32 kg1)
{
  const int i = blockIdx.x * 256 + threadIdx.x;
  const int r = i / CTX, t = i - r * CTX;
  const int b = r / NSAMP;
  const float dfv = df[b * CTX + t], lv = loc[b * CTX + t], sv = sc[b * CTX + t];
  const float z = normal_from_bits(jx_bits(kz0, kz1, NCTXS, (u32)i));
  u32 gk0, gk1;
  jx_subkey(kg0, kg1, NCTXS, (u32)i, gk0, gk1);
  const float g = jax_gamma_one(gk0, gk1, dfv * 0.5f);
  const float y = (lv + sv * (z * sqrtf(dfv / (2.0f * g)))) * tscale[b];
  yhat[(size_t)r * TM1 + t] = y;
}

// ---------------- kernel 5: persistent decode, occupancy probe --------------
// DROWS 16->8 (2 rows/wave, 3200 blocks) + unroll 8->4: targets VGPR <= 64
// spill-free to cross the {64,128} occupancy step (R14 at VGPR=108 showed
// OccupancyPercent ~20% ~= 1.6 blocks/CU; if residency is the limiter this
// doubles waves/SIMD). FMA order per gate unchanged -> bit-identical output.
__global__ void __launch_bounds__(256) dec_persist_kernel(
    const float* __restrict__ inp, const float* __restrict__ tscale,
    const float* __restrict__ WTx, const float* __restrict__ WT00,
    const float* __restrict__ WT10, const float* __restrict__ WT11,
    const float* __restrict__ bih0, const float* __restrict__ bhh0,
    const float* __restrict__ bih1, const float* __restrict__ bhh1,
    const float* __restrict__ wdf, const float* __restrict__ bdfp,
    const float* __restrict__ wloc, const float* __restrict__ blocp,
    const float* __restrict__ wsc, const float* __restrict__ bscp,
    const float* __restrict__ h0f, const float* __restrict__ c0f,
    const float* __restrict__ h1f, const float* __restrict__ c1f,
    const float* __restrict__ ct, const float* __restrict__ RND,
    float* __restrict__ yhat, u32 kl0, u32 kl1)
{
  const int t     = threadIdx.x;
  const int lane  = t & 63;
  const int w     = t >> 6;        // wave 0..3
  const int r0    = w * 2;         // wave's first local row
  const int gbase = lane << 2;     // first gate of this lane's 4-gate group

  __shared__ __align__(16) float g_s[DROWS][256];   // 8 KB
  __shared__ __align__(16) float hist[DROWS][64];   // 2 KB lag ring
  __shared__ float prevs[DROWS], tsr[DROWS];
  __shared__ float dfL[DROWS], locL[DROWS], scL[DROWS];

  const int base = blockIdx.x * DROWS;

  // ---- register-resident recurrent state (lane = unit) ----
  float h0reg[2], h1reg[2], c0reg[2], c1reg[2];
#pragma unroll
  for (int rr = 0; rr < 2; rr++) {
    const int bb = (base + r0 + rr) / NSAMP;
    h0reg[rr] = h0f[bb * 64 + lane];
    h1reg[rr] = h1f[bb * 64 + lane];
    c0reg[rr] = c0f[bb * 64 + lane];
    c1reg[rr] = c1f[bb * 64 + lane];
  }
  const float bs0 = bih0[lane]       + bhh0[lane];
  const float bs1 = bih0[64 + lane]  + bhh0[64 + lane];
  const float bs2 = bih0[128 + lane] + bhh0[128 + lane];
  const float bs3 = bih0[192 + lane] + bhh0[192 + lane];
  const float bs4 = bih1[lane]       + bhh1[lane];
  const float bs5 = bih1[64 + lane]  + bhh1[64 + lane];
  const float bs6 = bih1[128 + lane] + bhh1[128 + lane];
  const float bs7 = bih1[192 + lane] + bhh1[192 + lane];
  const float wdfv = wdf[lane], wlocv = wloc[lane], wscv = wsc[lane];
  const float bdf = bdfp[0], bloc = blocp[0], bsc = bscp[0];

  // ---- LDS init ----
  if (t < DROWS * 28) {
    const int i = t / 28, k = t - i * 28;
    const int bb = (base + i) / NSAMP;
    hist[i][63 - k] = ct[bb * CTX + 335 - k];
  }
  if (t < DROWS) {
    const int rg = base + t;
    prevs[t] = yhat[(size_t)rg * TM1 + 335];
    tsr[t] = tscale[rg / NSAMP];
  }
  __syncthreads();

  // ---- step loop (no barriers: all state wave-private) ----
  for (int s = 0; s < NSTEP; s++) {
    float xreg[2];
#pragma unroll
    for (int rr = 0; rr < 2; rr++) xreg[rr] = 0.0f;
    if (lane < 15) {
#pragma unroll
      for (int rr = 0; rr < 2; rr++) {
        const int row = r0 + rr;
        float v;
        if (lane == 0) {
          v = prevs[row] / tsr[row];
          hist[row][s & 63] = v;
        } else if (lane <= 10) {
          v = hist[row][(s - c_LAGS[lane - 1]) & 63];
        } else {
          const int bb = (base + row) / NSAMP;
          v = inp[((size_t)bb * TM1 + CTX + s) * NIN + lane];
        }
        xreg[rr] = v;
      }
    }

    // ---- G0: layer-0 gates (x part k=0..15, then Whh0 k=0..63) ----
    v2f aA[2], aB[2];
#pragma unroll
    for (int rr = 0; rr < 2; rr++) { aA[rr] = bc2(0.0f); aB[rr] = bc2(0.0f); }
#pragma unroll 4
    for (int k = 0; k < 16; k++) {
      const float4 wv = *(const float4*)&WTx[(k << 8) + gbase];
      v2f wlo, whi; wlo[0] = wv.x; wlo[1] = wv.y; whi[0] = wv.z; whi[1] = wv.w;
#pragma unroll
      for (int rr = 0; rr < 2; rr++) {
        const v2f hk = bc2(rl_f(xreg[rr], k));
        aA[rr] += wlo * hk; aB[rr] += whi * hk;
      }
    }
#pragma unroll 4
    for (int k = 0; k < 64; k++) {
      const float4 wv = *(const float4*)&WT00[(k << 8) + gbase];
      v2f wlo, whi; wlo[0] = wv.x; wlo[1] = wv.y; whi[0] = wv.z; whi[1] = wv.w;
#pragma unroll
      for (int rr = 0; rr < 2; rr++) {
        const v2f hk = bc2(rl_f(h0reg[rr], k));
        aA[rr] += wlo * hk; aB[rr] += whi * hk;
      }
    }
#pragma unroll
    for (int rr = 0; rr < 2; rr++) {
      float4 gv; gv.x = aA[rr][0]; gv.y = aA[rr][1]; gv.z = aB[rr][0]; gv.w = aB[rr][1];
      *(float4*)&g_s[r0 + rr][gbase] = gv;
    }

    // layer-0 elementwise (lane = unit; state in registers)
#pragma unroll
    for (int rr = 0; rr < 2; rr++) {
      const int row = r0 + rr;
      const float gi = g_s[row][lane]       + bs0;
      const float gf = g_s[row][64 + lane]  + bs1;
      const float gg = g_s[row][128 + lane] + bs2;
      const float go = g_s[row][192 + lane] + bs3;
      float c0 = c0reg[rr];
      c0 = sigm(gf) * c0 + sigm(gi) * tanhf(gg);
      c0reg[rr] = c0;
      h0reg[rr] = sigm(go) * tanhf(c0);
    }

    // ---- G1: layer-1 gates (Wih1·h0new k=0..63, then Whh1·h1 k=0..63) ----
#pragma unroll
    for (int rr = 0; rr < 2; rr++) { aA[rr] = bc2(0.0f); aB[rr] = bc2(0.0f); }
#pragma unroll 4
    for (int k = 0; k < 64; k++) {
      const float4 wv = *(const float4*)&WT10[(k << 8) + gbase];
      v2f wlo, whi; wlo[0] = wv.x; wlo[1] = wv.y; whi[0] = wv.z; whi[1] = wv.w;
#pragma unroll
      for (int rr = 0; rr < 2; rr++) {
        const v2f hk = bc2(rl_f(h0reg[rr], k));
        aA[rr] += wlo * hk; aB[rr] += whi * hk;
      }
    }
#pragma unroll 4
    for (int k = 0; k < 64; k++) {
      const float4 wv = *(const float4*)&WT11[(k << 8) + gbase];
      v2f wlo, whi; wlo[0] = wv.x; wlo[1] = wv.y; whi[0] = wv.z; whi[1] = wv.w;
#pragma unroll
      for (int rr = 0; rr < 2; rr++) {
        const v2f hk = bc2(rl_f(h1reg[rr], k));
        aA[rr] += wlo * hk; aB[rr] += whi * hk;
      }
    }
#pragma unroll
    for (int rr = 0; rr < 2; rr++) {
      float4 gv; gv.x = aA[rr][0]; gv.y = aA[rr][1]; gv.z = aB[rr][0]; gv.w = aB[rr][1];
      *(float4*)&g_s[r0 + rr][gbase] = gv;
    }

    // layer-1 elementwise + head
#pragma unroll
    for (int rr = 0; rr < 2; rr++) {
      const int row = r0 + rr;
      const float gi = g_s[row][lane]       + bs4;
      const float gf = g_s[row][64 + lane]  + bs5;
      const float gg = g_s[row][128 + lane] + bs6;
      const float go = g_s[row][192 + lane] + bs7;
      float c1 = c1reg[rr];
      c1 = sigm(gf) * c1 + sigm(gi) * tanhf(gg);
      c1reg[rr] = c1;
      const float h1v = sigm(go) * tanhf(c1);
      h1reg[rr] = h1v;
      float pd = h1v * wdfv, pl = h1v * wlocv, ps = h1v * wscv;
#pragma unroll
      for (int off = 32; off > 0; off >>= 1) {
        pd += __shfl_down(pd, off, 64);
        pl += __shfl_down(pl, off, 64);
        ps += __shfl_down(ps, off, 64);
      }
      if (lane == 0) {
        dfL[row]  = 2.0f + softplusf(pd + bdf);
        locL[row] = pl + bloc;
        scL[row]  = softplusf(ps + bsc);
      }
    }

    // sampling: lanes 0..1 consume precomputed randoms (fallback ~3%)
    if (lane < 2) {
      const int row = r0 + lane, rg = base + row;
      const float dfv = dfL[row], lv = locL[row], scv = scL[row];
      const float* Rp = RND + ((size_t)s * RTOT + rg) * 4;
      const float z = Rp[0];
      const float alpha = dfv * 0.5f;   // >= 1 always: df = 2 + softplus > 2
      float gam;
      {
#pragma clang fp contract(off)
        const float d = alpha - 0.33333334f;
        const float c = 0.33333334f / sqrtf(d);
        float x = Rp[1];
        float v = 1.0f + x * c;
        bool ok = true;
        if (v <= 0.0f) { x = Rp[2]; v = 1.0f + x * c; ok = (v > 0.0f); }
        const float X = x * x;
        const float V = (v * v) * v;
        const float U = Rp[3];
        bool accept = false;
        if (ok) {
          if (!(U >= 1.0f - 0.0331f * (X * X))) accept = true;
          else if (!(logf(U) >= 0.5f * X + d * ((1.0f - V) + logf(V)))) accept = true;
        }
        if (accept) {
          gam = d * V;   // boost = 1 (alpha >= 1), matches reference exactly
        } else {
          u32 ks0, ks1, skg0, skg1, gk0, gk1;
          tf2x32(kl0, kl1, 0u, (u32)s, ks0, ks1);
          tf2x32(ks0, ks1, 0u, 1u, skg0, skg1);
          jx_subkey(skg0, skg1, RTOT, (u32)rg, gk0, gk1);
          gam = jax_gamma_one(gk0, gk1, alpha);
        }
      }
      const float y = (lv + scv * (z * sqrtf(dfv / (2.0f * gam)))) * tsr[row];
      yhat[(size_t)rg * TM1 + CTX + s] = y;
      prevs[row] = y;
    }
  }
}

// ---------------- kernel 6: median over 100 samples per (b,t) ----------------
__global__ void __launch_bounds__(256) median_kernel(
    const float* __restrict__ yhat, float* __restrict__ out)
{
  __shared__ float vals[4][100];
  const int wave = threadIdx.x >> 6, lane = threadIdx.x & 63;
  const int cell = blockIdx.x * 4 + wave;
  const int b = cell / TM1, t = cell - b * TM1;
  const float* basep = yhat + (size_t)b * NSAMP * TM1 + t;
  const float v1 = basep[(size_t)lane * TM1];
  vals[wave][lane] = v1;
  float v2 = 0.f;
  if (lane < 36) { v2 = basep[(size_t)(64 + lane) * TM1]; vals[wave][64 + lane] = v2; }
  __syncthreads();
  int cl1 = 0, ce1 = 0, cl2 = 0, ce2 = 0;
  for (int jj = 0; jj < 100; jj++) {
    const float w = vals[wave][jj];
    cl1 += (w < v1); ce1 += (w == v1);
    cl2 += (w < v2); ce2 += (w == v2);
  }
  if (cl1 <= 49 && 49 < cl1 + ce1) out[cell] = v1;
  if (lane < 36 && cl2 <= 49 && 49 < cl2 + ce2) out[cell] = v2;
}

// ---------------- launch ----------------
extern "C" void kernel_launch(void* const* d_in, const int* in_sizes, int n_in,
                              void* d_out, int out_size, void* d_ws, size_t ws_size,
                              hipStream_t stream) {
  (void)in_sizes; (void)n_in; (void)out_size; (void)ws_size;
  const float* X     = (const float*)d_in[0];
  const float* Wih0  = (const float*)d_in[2];
  const float* Whh0  = (const float*)d_in[3];
  const float* bih0  = (const float*)d_in[4];
  const float* bhh0  = (const float*)d_in[5];
  const float* Wih1  = (const float*)d_in[6];
  const float* Whh1  = (const float*)d_in[7];
  const float* bih1  = (const float*)d_in[8];
  const float* bhh1  = (const float*)d_in[9];
  const float* wdf   = (const float*)d_in[10];
  const float* bdf   = (const float*)d_in[11];
  const float* wloc  = (const float*)d_in[12];
  const float* bloc  = (const float*)d_in[13];
  const float* wsc   = (const float*)d_in[14];
  const float* bsc   = (const float*)d_in[15];
  const float* emb   = (const float*)d_in[16];

  float* wsf = (float*)d_ws;
  float* inp  = wsf + OFF_INP;
  float* ct   = wsf + OFF_CT;
  float* ts   = wsf + OFF_TS;
  float* lts  = wsf + OFF_LTS;
  float* dfp  = wsf + OFF_DF;
  float* locp = wsf + OFF_LOC;
  float* scp  = wsf + OFF_SC;
  float* h0f  = wsf + OFF_H0F;
  float* c0f  = wsf + OFF_C0F;
  float* h1f  = wsf + OFF_H1F;
  float* c1f  = wsf + OFF_C1F;
  float* yhat = wsf + OFF_YH;
  float* wtx  = wsf + OFF_WTX;
  float* wt00 = wsf + OFF_WT00;
  float* wt10 = wsf + OFF_WT10;
  float* wt11 = wsf + OFF_WT11;
  float* rnd  = wsf + OFF_RND;

  const u32 key0 = 0u, key1 = 42u;
  u32 kc0, kc1, kl0, kl1;
  jx_subkey(key0, key1, 2u, 0u, kc0, kc1);
  jx_subkey(key0, key1, 2u, 1u, kl0, kl1);
  u32 kz0, kz1, kg0, kg1;
  jx_subkey(kc0, kc1, 2u, 0u, kz0, kz1);
  jx_subkey(kc0, kc1, 2u, 1u, kg0, kg1);

  wtrans_kernel<<<208, 256, 0, stream>>>(Wih0, Whh0, Wih1, Whh1, wtx, wt00, wt10, wt11);
  rnd_dec_kernel<<<(NSTEP * RTOT) / 256, 256, 0, stream>>>(rnd, kl0, kl1);
  prep_kernel<<<NB, 256, 0, stream>>>(X, emb, inp, ct, ts, lts);
  ctx_lstm_kernel<<<NB, 256, 0, stream>>>(inp, wtx, wt00, wt10, wt11,
                                          bih0, bhh0, bih1, bhh1,
                                          wdf, bdf, wloc, bloc, wsc, bsc,
                                          dfp, locp, scp, h0f, c0f, h1f, c1f);
  ctx_sample_kernel<<<NCTXS / 256, 256, 0, stream>>>(dfp, locp, scp, ts, yhat, kz0, kz1, kg0, kg1);
  dec_persist_kernel<<<DBLOCKS, 256, 0, stream>>>(inp, ts, wtx, wt00, wt10, wt11,
                                                  bih0, bhh0, bih1, bhh1,
                                                  wdf, bdf, wloc, bloc, wsc, bsc,
                                                  h0f, c0f, h1f, c1f, ct, rnd, yhat, kl0, kl1);
  median_kernel<<<(NB * TM1) / 4, 256, 0, stream>>>(yhat, (float*)d_out);
}

// Round 16
// 5122.033 us; speedup vs baseline: 1.1034x; 1.1034x over previous
//
#include <hip/hip_runtime.h>
#include <stdint.h>
#include <stddef.h>

typedef uint32_t u32;
typedef float v2f __attribute__((ext_vector_type(2)));

// ---------------- problem constants (fixed by reference file) ----------------
#define NB    256      // batch B
#define LFULL 412      // L
#define NCH   3        // C
#define CTX   336      // context_length
#define NSAMP 100      // n_samples
#define TM1   383      // T-1 (T = L - MAX_LAG = 384)
#define HID   64
#define NIN   15
#define RTOT  25600    // NB*NSAMP
#define NCTXS 8601600u // RTOT*CTX
#define NSTEP 47       // H-1

#define DROWS   16     // rows per persistent decode block (4 per wave) — R14 optimum
#define DBLOCKS (RTOT / DROWS)  // 1600

#define JAX_PARTITIONABLE 1

__device__ const int c_LAGS[10] = {1,2,3,4,5,6,7,14,21,28};

__device__ inline v2f bc2(float x) { v2f r; r[0] = x; r[1] = x; return r; }

// ---------------- threefry2x32 (matches jax._src.prng) ----------------
__host__ __device__ inline void tf2x32(u32 k0, u32 k1, u32 x0, u32 x1, u32& o0, u32& o1) {
  const u32 ks2 = k0 ^ k1 ^ 0x1BD11BDAu;
#define TFR(r) { x0 += x1; x1 = (x1 << (r)) | (x1 >> (32 - (r))); x1 ^= x0; }
  x0 += k0; x1 += k1;
  TFR(13) TFR(15) TFR(26) TFR(6)
  x0 += k1; x1 += ks2 + 1u;
  TFR(17) TFR(29) TFR(16) TFR(24)
  x0 += ks2; x1 += k0 + 2u;
  TFR(13) TFR(15) TFR(26) TFR(6)
  x0 += k0; x1 += k1 + 3u;
  TFR(17) TFR(29) TFR(16) TFR(24)
  x0 += k1; x1 += ks2 + 4u;
  TFR(13) TFR(15) TFR(26) TFR(6)
  x0 += ks2; x1 += k0 + 5u;
#undef TFR
  o0 = x0; o1 = x1;
}

__host__ __device__ inline u32 split_word_legacy(u32 k0, u32 k1, u32 n, u32 j) {
  u32 o0, o1;
  if (j < n) { tf2x32(k0, k1, j, n + j, o0, o1); return o0; }
  tf2x32(k0, k1, j - n, j, o0, o1); return o1;
}

__host__ __device__ inline void jx_subkey(u32 k0, u32 k1, u32 n, u32 i, u32& s0, u32& s1) {
#if JAX_PARTITIONABLE
  (void)n; tf2x32(k0, k1, 0u, i, s0, s1);
#else
  s0 = split_word_legacy(k0, k1, n, 2u * i);
  s1 = split_word_legacy(k0, k1, n, 2u * i + 1u);
#endif
}

__device__ inline u32 jx_bits(u32 k0, u32 k1, u32 n, u32 i) {
#if JAX_PARTITIONABLE
  (void)n; u32 o0, o1; tf2x32(k0, k1, 0u, i, o0, o1); return o0 ^ o1;
#else
  u32 o0, o1;
  if (n == 1u) { tf2x32(k0, k1, 0u, 0u, o0, o1); return o0; }
  const u32 h = n >> 1;
  if (i < h) { tf2x32(k0, k1, i, h + i, o0, o1); return o0; }
  tf2x32(k0, k1, i - h, i, o0, o1); return o1;
#endif
}

// ---------------- JAX-exact float transforms ----------------
__device__ inline float jax_erfinv(float x) {
#pragma clang fp contract(off)
  float w = -log1pf(-x * x);
  float p;
  if (w < 5.0f) {
    w = w - 2.5f;
    p = 2.81022636e-08f;
    p = 3.43273939e-07f + p * w;
    p = -3.5233877e-06f + p * w;
    p = -4.39150654e-06f + p * w;
    p = 0.00021858087f + p * w;
    p = -0.00125372503f + p * w;
    p = -0.00417768164f + p * w;
    p = 0.246640727f + p * w;
    p = 1.50140941f + p * w;
  } else {
    w = sqrtf(w) - 3.0f;
    p = -0.000200214257f;
    p = 0.000100950558f + p * w;
    p = 0.00134934322f + p * w;
    p = -0.00367342844f + p * w;
    p = 0.00573950773f + p * w;
    p = -0.0076224613f + p * w;
    p = 0.00943887047f + p * w;
    p = 1.00167406f + p * w;
    p = 2.83297682f + p * w;
  }
  return p * x;
}

__device__ inline float u01_from_bits(u32 bits) {
  return __uint_as_float((bits >> 9) | 0x3f800000u) - 1.0f;
}

__device__ inline float normal_from_bits(u32 bits) {
#pragma clang fp contract(off)
  const float lo = -0.99999994f;
  const float u = u01_from_bits(bits);
  float r = u * 2.0f + lo;
  r = fmaxf(lo, r);
  return 1.41421356f * jax_erfinv(r);
}

__device__ float jax_gamma_one(u32 k0, u32 k1, float alpha) {
#pragma clang fp contract(off)
  const bool boost_mask = (alpha >= 1.0f);
  const float alpha_orig = alpha;
  const float a = boost_mask ? alpha : (alpha + 1.0f);
  const float d = a - 0.33333334f;
  const float c = 0.33333334f / sqrtf(d);
  u32 K0, K1, S0, S1;
  jx_subkey(k0, k1, 2u, 0u, K0, K1);
  jx_subkey(k0, k1, 2u, 1u, S0, S1);
  float u_boost = 1.0f;
  if (!boost_mask) u_boost = u01_from_bits(jx_bits(S0, S1, 1u, 0u));
  float X = 0.0f, V = 1.0f, U = 2.0f;
  while (true) {
    if (!(U >= 1.0f - 0.0331f * (X * X))) break;
    if (!(logf(U) >= 0.5f * X + d * ((1.0f - V) + logf(V)))) break;
    u32 nk0, nk1, xk0, xk1, uk0, uk1;
    jx_subkey(K0, K1, 3u, 0u, nk0, nk1);
    jx_subkey(K0, K1, 3u, 1u, xk0, xk1);
    jx_subkey(K0, K1, 3u, 2u, uk0, uk1);
    K0 = nk0; K1 = nk1;
    float x, v;
    u32 c0 = xk0, c1 = xk1;
    do {
      u32 t0, t1, s0, s1;
      jx_subkey(c0, c1, 2u, 0u, t0, t1);
      jx_subkey(c0, c1, 2u, 1u, s0, s1);
      c0 = t0; c1 = t1;
      x = normal_from_bits(jx_bits(s0, s1, 1u, 0u));
      v = 1.0f + x * c;
    } while (v <= 0.0f);
    X = x * x;
    V = (v * v) * v;
    U = u01_from_bits(jx_bits(uk0, uk1, 1u, 0u));
  }
  const float sample = d * V;
  const float boost = boost_mask ? 1.0f : powf(u_boost, 1.0f / alpha_orig);
  return sample * boost;
}

__device__ inline float sigm(float x) { return 1.0f / (1.0f + expf(-x)); }
__device__ inline float softplusf(float x) { return fmaxf(x, 0.0f) + log1pf(expf(-fabsf(x))); }

// cross-lane broadcast on the VALU pipe (not DS): v_readlane -> SGPR
__device__ inline float rl_f(float v, int l) {
  return __int_as_float(__builtin_amdgcn_readlane(__float_as_int(v), l));
}

// ---------------- workspace layout (floats) ----------------
enum : size_t {
  OFF_INP  = 0,
  OFF_CT   = OFF_INP + (size_t)NB * TM1 * NIN,
  OFF_TS   = OFF_CT + (size_t)NB * CTX,
  OFF_LTS  = OFF_TS + NB,
  OFF_DF   = OFF_LTS + NB,
  OFF_LOC  = OFF_DF + (size_t)NB * CTX,
  OFF_SC   = OFF_LOC + (size_t)NB * CTX,
  OFF_H0F  = OFF_SC + (size_t)NB * CTX,
  OFF_C0F  = OFF_H0F + (size_t)NB * HID,
  OFF_H1F  = OFF_C0F + (size_t)NB * HID,
  OFF_C1F  = OFF_H1F + (size_t)NB * HID,
  OFF_YH   = OFF_C1F + (size_t)NB * HID,
  OFF_WTX  = OFF_YH + (size_t)RTOT * TM1,     // Wih0^T padded [16][256]
  OFF_WT00 = OFF_WTX + 4096,                  // Whh0^T [64][256]
  OFF_WT10 = OFF_WT00 + 16384,                // Wih1^T [64][256]
  OFF_WT11 = OFF_WT10 + 16384,                // Whh1^T [64][256]
  OFF_RND  = OFF_WT11 + 16384,                // decode randoms [NSTEP][RTOT][4]
  WS_FLOATS = OFF_RND + (size_t)NSTEP * RTOT * 4   // ~16.6M floats ~66 MB
};

// ---------------- kernel 0a: transpose weights to [k][gate] ------------------
__global__ void __launch_bounds__(256) wtrans_kernel(
    const float* __restrict__ Wih0, const float* __restrict__ Whh0,
    const float* __restrict__ Wih1, const float* __restrict__ Whh1,
    float* __restrict__ WTx, float* __restrict__ WT00,
    float* __restrict__ WT10, float* __restrict__ WT11)
{
  const int i = blockIdx.x * 256 + threadIdx.x;   // < 53248
  if (i < 4096) {
    const int k = i >> 8, g = i & 255;
    WTx[i] = (k < 15) ? Wih0[g * 15 + k] : 0.0f;
  } else if (i < 4096 + 16384) {
    const int j = i - 4096, k = j >> 8, g = j & 255;
    WT00[j] = Whh0[g * 64 + k];
  } else if (i < 4096 + 32768) {
    const int j = i - 4096 - 16384, k = j >> 8, g = j & 255;
    WT10[j] = Wih1[g * 64 + k];
  } else {
    const int j = i - 4096 - 32768, k = j >> 8, g = j & 255;
    WT11[j] = Whh1[g * 64 + k];
  }
}

// ---------------- kernel 0b: precompute decode randoms -----------------------
__global__ void __launch_bounds__(256) rnd_dec_kernel(
    float* __restrict__ RND, u32 kl0, u32 kl1)
{
  const int i = blockIdx.x * 256 + threadIdx.x;   // < NSTEP*RTOT = 1203200
  const int s = i / RTOT, rg = i - s * RTOT;
  u32 ks0, ks1, skz0, skz1, skg0, skg1;
  tf2x32(kl0, kl1, 0u, (u32)s, ks0, ks1);
  tf2x32(ks0, ks1, 0u, 0u, skz0, skz1);
  tf2x32(ks0, ks1, 0u, 1u, skg0, skg1);
  const float z = normal_from_bits(jx_bits(skz0, skz1, RTOT, (u32)rg));
  u32 gk0, gk1;
  jx_subkey(skg0, skg1, RTOT, (u32)rg, gk0, gk1);
  u32 K0, K1, S0, S1;
  jx_subkey(gk0, gk1, 2u, 0u, K0, K1);
  jx_subkey(gk0, gk1, 2u, 1u, S0, S1);   // boost key, unused (alpha >= 1)
  u32 nk0, nk1, xk0, xk1, uk0, uk1;
  jx_subkey(K0, K1, 3u, 0u, nk0, nk1);
  jx_subkey(K0, K1, 3u, 1u, xk0, xk1);
  jx_subkey(K0, K1, 3u, 2u, uk0, uk1);
  u32 c0 = xk0, c1 = xk1, t0, t1, s0, s1;
  jx_subkey(c0, c1, 2u, 0u, t0, t1);
  jx_subkey(c0, c1, 2u, 1u, s0, s1);
  const float x1 = normal_from_bits(jx_bits(s0, s1, 1u, 0u));
  c0 = t0; c1 = t1;
  jx_subkey(c0, c1, 2u, 0u, t0, t1);
  jx_subkey(c0, c1, 2u, 1u, s0, s1);
  const float x2 = normal_from_bits(jx_bits(s0, s1, 1u, 0u));
  const float U1 = u01_from_bits(jx_bits(uk0, uk1, 1u, 0u));
  float* R = RND + (size_t)i * 4;
  R[0] = z; R[1] = x1; R[2] = x2; R[3] = U1;
}

// ---------------- kernel 1: tscale + feature build ----------------
__global__ void __launch_bounds__(256) prep_kernel(
    const float* __restrict__ X, const float* __restrict__ emb,
    float* __restrict__ inp, float* __restrict__ ct,
    float* __restrict__ tscale, float* __restrict__ ltscale)
{
  const int b = blockIdx.x, t = threadIdx.x;
  __shared__ float red[256];
  __shared__ float ts_sh;
  const float* Xb = X + (size_t)b * LFULL * NCH;
  float p = fabsf(Xb[(28 + t) * NCH]);
  if (t < 80) p += fabsf(Xb[(28 + 256 + t) * NCH]);
  red[t] = p;
  for (int st = 128; st > 0; st >>= 1) { __syncthreads(); if (t < st) red[t] += red[t + st]; }
  __syncthreads();
  if (t == 0) {
    float ts = red[0] / 336.0f;
    ts = fmaxf(ts, 1e-10f);
    tscale[b] = ts; ltscale[b] = logf(ts); ts_sh = ts;
  }
  __syncthreads();
  const float ts = ts_sh;
  const float lts = logf(ts);
  const float ev = emb[0];
  for (int idx = t; idx < TM1 * NIN; idx += 256) {
    const int tt = idx / NIN, f = idx - tt * NIN;
    float val;
    if (f == 0)       val = (tt < CTX) ? Xb[(28 + tt) * NCH] / ts : 0.0f;
    else if (f <= 10) val = (tt < CTX) ? Xb[(28 + tt - c_LAGS[f - 1]) * NCH] / ts : 0.0f;
    else if (f == 11) val = ev;
    else if (f == 12) val = Xb[(28 + tt) * NCH + 2];
    else if (f == 13) val = lts;
    else              val = Xb[(28 + tt) * NCH + 1];
    inp[(size_t)(b * TM1 + tt) * NIN + f] = val;
    if (f == 0 && tt < CTX) ct[b * CTX + tt] = val;
  }
}

// ---------------- kernel 2: context LSTM, dec-style streaming (R14) ---------
__global__ void __launch_bounds__(256) ctx_lstm_kernel(
    const float* __restrict__ inp,
    const float* __restrict__ WTx, const float* __restrict__ WT00,
    const float* __restrict__ WT10, const float* __restrict__ WT11,
    const float* __restrict__ bih0, const float* __restrict__ bhh0,
    const float* __restrict__ bih1, const float* __restrict__ bhh1,
    const float* __restrict__ wdf, const float* __restrict__ bdfp,
    const float* __restrict__ wloc, const float* __restrict__ blocp,
    const float* __restrict__ wsc, const float* __restrict__ bscp,
    float* __restrict__ dfo, float* __restrict__ loco, float* __restrict__ sco,
    float* __restrict__ h0f, float* __restrict__ c0f,
    float* __restrict__ h1f, float* __restrict__ c1f)
{
  const int b = blockIdx.x, t = threadIdx.x;
  const int lane = t & 63, w = t >> 6;
  const int gbase = lane << 2;
  __shared__ __align__(16) float gA[4][256];
  __shared__ __align__(16) float gB[4][256];

  const float bs0 = bih0[lane]       + bhh0[lane];
  const float bs1 = bih0[64 + lane]  + bhh0[64 + lane];
  const float bs2 = bih0[128 + lane] + bhh0[128 + lane];
  const float bs3 = bih0[192 + lane] + bhh0[192 + lane];
  const float bs4 = bih1[lane]       + bhh1[lane];
  const float bs5 = bih1[64 + lane]  + bhh1[64 + lane];
  const float bs6 = bih1[128 + lane] + bhh1[128 + lane];
  const float bs7 = bih1[192 + lane] + bhh1[192 + lane];
  const float wdfv = wdf[lane], wlocv = wloc[lane], wscv = wsc[lane];
  const float bdf = bdfp[0], bloc = blocp[0], bsc = bscp[0];

  float h0r = 0.f, h1r = 0.f, c0r = 0.f, c1r = 0.f;
  const float* inb = inp + (size_t)b * TM1 * NIN;
  const int kx = w * 4;    // x-part k-quarter
  const int kh = w * 16;   // h-part k-quarter

  for (int tt = 0; tt < CTX; tt++) {
    float xr = 0.f;
    if (lane < 15) xr = inb[tt * NIN + lane];

    v2f aA = bc2(0.0f), aB = bc2(0.0f);
#pragma unroll
    for (int kk = 0; kk < 4; kk++) {
      const int k = kx + kk;
      const float4 wv = *(const float4*)&WTx[(k << 8) + gbase];
      v2f wlo, whi; wlo[0] = wv.x; wlo[1] = wv.y; whi[0] = wv.z; whi[1] = wv.w;
      const v2f hk = bc2(rl_f(xr, k));
      aA += wlo * hk; aB += whi * hk;
    }
#pragma unroll
    for (int kk = 0; kk < 16; kk++) {
      const int k = kh + kk;
      const float4 wv = *(const float4*)&WT00[(k << 8) + gbase];
      v2f wlo, whi; wlo[0] = wv.x; wlo[1] = wv.y; whi[0] = wv.z; whi[1] = wv.w;
      const v2f hk = bc2(rl_f(h0r, k));
      aA += wlo * hk; aB += whi * hk;
    }
    {
      float4 gv; gv.x = aA[0]; gv.y = aA[1]; gv.z = aB[0]; gv.w = aB[1];
      *(float4*)&gA[w][gbase] = gv;
    }
    __syncthreads();

    {
      float gi = ((gA[0][lane]       + gA[1][lane])       + gA[2][lane])       + gA[3][lane];
      float gf = ((gA[0][64 + lane]  + gA[1][64 + lane])  + gA[2][64 + lane])  + gA[3][64 + lane];
      float gg = ((gA[0][128 + lane] + gA[1][128 + lane]) + gA[2][128 + lane]) + gA[3][128 + lane];
      float go = ((gA[0][192 + lane] + gA[1][192 + lane]) + gA[2][192 + lane]) + gA[3][192 + lane];
      gi += bs0; gf += bs1; gg += bs2; go += bs3;
      c0r = sigm(gf) * c0r + sigm(gi) * tanhf(gg);
      h0r = sigm(go) * tanhf(c0r);
    }

    aA = bc2(0.0f); aB = bc2(0.0f);
#pragma unroll
    for (int kk = 0; kk < 16; kk++) {
      const int k = kh + kk;
      const float4 wv = *(const float4*)&WT10[(k << 8) + gbase];
      v2f wlo, whi; wlo[0] = wv.x; wlo[1] = wv.y; whi[0] = wv.z; whi[1] = wv.w;
      const v2f hk = bc2(rl_f(h0r, k));
      aA += wlo * hk; aB += whi * hk;
    }
#pragma unroll
    for (int kk = 0; kk < 16; kk++) {
      const int k = kh + kk;
      const float4 wv = *(const float4*)&WT11[(k << 8) + gbase];
      v2f wlo, whi; wlo[0] = wv.x; wlo[1] = wv.y; whi[0] = wv.z; whi[1] = wv.w;
      const v2f hk = bc2(rl_f(h1r, k));
      aA += wlo * hk; aB += whi * hk;
    }
    {
      float4 gv; gv.x = aA[0]; gv.y = aA[1]; gv.z = aB[0]; gv.w = aB[1];
      *(float4*)&gB[w][gbase] = gv;
    }
    __syncthreads();

    {
      float gi = ((gB[0][lane]       + gB[1][lane])       + gB[2][lane])       + gB[3][lane];
      float gf = ((gB[0][64 + lane]  + gB[1][64 + lane])  + gB[2][64 + lane])  + gB[3][64 + lane];
      float gg = ((gB[0][128 + lane] + gB[1][128 + lane]) + gB[2][128 + lane]) + gB[3][128 + lane];
      float go = ((gB[0][192 + lane] + gB[1][192 + lane]) + gB[2][192 + lane]) + gB[3][192 + lane];
      gi += bs4; gf += bs5; gg += bs6; go += bs7;
      c1r = sigm(gf) * c1r + sigm(gi) * tanhf(gg);
      h1r = sigm(go) * tanhf(c1r);
      if (w == 0) {
        float pd = h1r * wdfv, pl = h1r * wlocv, ps = h1r * wscv;
#pragma unroll
        for (int off = 32; off > 0; off >>= 1) {
          pd += __shfl_down(pd, off, 64);
          pl += __shfl_down(pl, off, 64);
          ps += __shfl_down(ps, off, 64);
        }
        if (lane == 0) {
          dfo[b * CTX + tt]  = 2.0f + softplusf(pd + bdf);
          loco[b * CTX + tt] = pl + bloc;
          sco[b * CTX + tt]  = softplusf(ps + bsc);
        }
      }
    }
  }
  if (w == 0) {
    h0f[b * 64 + lane] = h0r; c0f[b * 64 + lane] = c0r;
    h1f[b * 64 + lane] = h1r; c1f[b * 64 + lane] = c1r;
  }
}

// ---------------- kernel 3: context sampling (y_ctx) ----------------
__global__ void __launch_bounds__(256) ctx_sample_kernel(
    const float* __restrict__ df, const float* __restrict__ loc, const float* __restrict__ sc,
    const float* __restrict__ tscale, float* __restrict__ yhat,
    u32 kz0, u32 kz1, u32 kg0, u32 kg1)
{
  const int i = blockIdx.x * 256 + threadIdx.x;
  const int r = i / CTX, t = i - r * CTX;
  const int b = r / NSAMP;
  const float dfv = df[b * CTX + t], lv = loc[b * CTX + t], sv = sc[b * CTX + t];
  const float z = normal_from_bits(jx_bits(kz0, kz1, NCTXS, (u32)i));
  u32 gk0, gk1;
  jx_subkey(kg0, kg1, NCTXS, (u32)i, gk0, gk1);
  const float g = jax_gamma_one(gk0, gk1, dfv * 0.5f);
  const float y = (lv + sv * (z * sqrtf(dfv / (2.0f * g)))) * tscale[b];
  yhat[(size_t)r * TM1 + t] = y;
}

// ---------------- kernel 5: persistent decode (R14 optimum, restored) -------
// DROWS=16 (4 rows/wave): measured optimum of the rows/wave sweep
// (32->4.6ms, 16->4.14ms, 8->4.8ms). Register h/c, readlane broadcasts,
// coalesced WT stream, precomputed randoms, packed v2f accumulators,
// no in-loop barriers. VGPR 108, VALU-issue-bound at 76%.
__global__ void __launch_bounds__(256) dec_persist_kernel(
    const float* __restrict__ inp, const float* __restrict__ tscale,
    const float* __restrict__ WTx, const float* __restrict__ WT00,
    const float* __restrict__ WT10, const float* __restrict__ WT11,
    const float* __restrict__ bih0, const float* __restrict__ bhh0,
    const float* __restrict__ bih1, const float* __restrict__ bhh1,
    const float* __restrict__ wdf, const float* __restrict__ bdfp,
    const float* __restrict__ wloc, const float* __restrict__ blocp,
    const float* __restrict__ wsc, const float* __restrict__ bscp,
    const float* __restrict__ h0f, const float* __restrict__ c0f,
    const float* __restrict__ h1f, const float* __restrict__ c1f,
    const float* __restrict__ ct, const float* __restrict__ RND,
    float* __restrict__ yhat, u32 kl0, u32 kl1)
{
  const int t     = threadIdx.x;
  const int lane  = t & 63;
  const int w     = t >> 6;        // wave 0..3
  const int r0    = w * 4;         // wave's first local row
  const int gbase = lane << 2;     // first gate of this lane's 4-gate group

  __shared__ __align__(16) float g_s[DROWS][256];   // 16 KB
  __shared__ __align__(16) float hist[DROWS][64];   // 4 KB lag ring
  __shared__ float prevs[DROWS], tsr[DROWS];
  __shared__ float dfL[DROWS], locL[DROWS], scL[DROWS];

  const int base = blockIdx.x * DROWS;

  float h0reg[4], h1reg[4], c0reg[4], c1reg[4];
#pragma unroll
  for (int rr = 0; rr < 4; rr++) {
    const int bb = (base + r0 + rr) / NSAMP;
    h0reg[rr] = h0f[bb * 64 + lane];
    h1reg[rr] = h1f[bb * 64 + lane];
    c0reg[rr] = c0f[bb * 64 + lane];
    c1reg[rr] = c1f[bb * 64 + lane];
  }
  const float bs0 = bih0[lane]       + bhh0[lane];
  const float bs1 = bih0[64 + lane]  + bhh0[64 + lane];
  const float bs2 = bih0[128 + lane] + bhh0[128 + lane];
  const float bs3 = bih0[192 + lane] + bhh0[192 + lane];
  const float bs4 = bih1[lane]       + bhh1[lane];
  const float bs5 = bih1[64 + lane]  + bhh1[64 + lane];
  const float bs6 = bih1[128 + lane] + bhh1[128 + lane];
  const float bs7 = bih1[192 + lane] + bhh1[192 + lane];
  const float wdfv = wdf[lane], wlocv = wloc[lane], wscv = wsc[lane];
  const float bdf = bdfp[0], bloc = blocp[0], bsc = bscp[0];

  for (int idx = t; idx < DROWS * 28; idx += 256) {
    const int i = idx / 28, k = idx - i * 28;
    const int bb = (base + i) / NSAMP;
    hist[i][63 - k] = ct[bb * CTX + 335 - k];
  }
  if (t < DROWS) {
    const int rg = base + t;
    prevs[t] = yhat[(size_t)rg * TM1 + 335];
    tsr[t] = tscale[rg / NSAMP];
  }
  __syncthreads();

  for (int s = 0; s < NSTEP; s++) {
    float xreg[4];
#pragma unroll
    for (int rr = 0; rr < 4; rr++) xreg[rr] = 0.0f;
    if (lane < 15) {
#pragma unroll
      for (int rr = 0; rr < 4; rr++) {
        const int row = r0 + rr;
        float v;
        if (lane == 0) {
          v = prevs[row] / tsr[row];
          hist[row][s & 63] = v;
        } else if (lane <= 10) {
          v = hist[row][(s - c_LAGS[lane - 1]) & 63];
        } else {
          const int bb = (base + row) / NSAMP;
          v = inp[((size_t)bb * TM1 + CTX + s) * NIN + lane];
        }
        xreg[rr] = v;
      }
    }

    v2f aA[4], aB[4];
#pragma unroll
    for (int rr = 0; rr < 4; rr++) { aA[rr] = bc2(0.0f); aB[rr] = bc2(0.0f); }
#pragma unroll
    for (int k = 0; k < 16; k++) {
      const float4 wv = *(const float4*)&WTx[(k << 8) + gbase];
      v2f wlo, whi; wlo[0] = wv.x; wlo[1] = wv.y; whi[0] = wv.z; whi[1] = wv.w;
#pragma unroll
      for (int rr = 0; rr < 4; rr++) {
        const v2f hk = bc2(rl_f(xreg[rr], k));
        aA[rr] += wlo * hk; aB[rr] += whi * hk;
      }
    }
#pragma unroll 8
    for (int k = 0; k < 64; k++) {
      const float4 wv = *(const float4*)&WT00[(k << 8) + gbase];
      v2f wlo, whi; wlo[0] = wv.x; wlo[1] = wv.y; whi[0] = wv.z; whi[1] = wv.w;
#pragma unroll
      for (int rr = 0; rr < 4; rr++) {
        const v2f hk = bc2(rl_f(h0reg[rr], k));
        aA[rr] += wlo * hk; aB[rr] += whi * hk;
      }
    }
#pragma unroll
    for (int rr = 0; rr < 4; rr++) {
      float4 gv; gv.x = aA[rr][0]; gv.y = aA[rr][1]; gv.z = aB[rr][0]; gv.w = aB[rr][1];
      *(float4*)&g_s[r0 + rr][gbase] = gv;
    }

#pragma unroll
    for (int rr = 0; rr < 4; rr++) {
      const int row = r0 + rr;
      const float gi = g_s[row][lane]       + bs0;
      const float gf = g_s[row][64 + lane]  + bs1;
      const float gg = g_s[row][128 + lane] + bs2;
      const float go = g_s[row][192 + lane] + bs3;
      float c0 = c0reg[rr];
      c0 = sigm(gf) * c0 + sigm(gi) * tanhf(gg);
      c0reg[rr] = c0;
      h0reg[rr] = sigm(go) * tanhf(c0);
    }

#pragma unroll
    for (int rr = 0; rr < 4; rr++) { aA[rr] = bc2(0.0f); aB[rr] = bc2(0.0f); }
#pragma unroll 8
    for (int k = 0; k < 64; k++) {
      const float4 wv = *(const float4*)&WT10[(k << 8) + gbase];
      v2f wlo, whi; wlo[0] = wv.x; wlo[1] = wv.y; whi[0] = wv.z; whi[1] = wv.w;
#pragma unroll
      for (int rr = 0; rr < 4; rr++) {
        const v2f hk = bc2(rl_f(h0reg[rr], k));
        aA[rr] += wlo * hk; aB[rr] += whi * hk;
      }
    }
#pragma unroll 8
    for (int k = 0; k < 64; k++) {
      const float4 wv = *(const float4*)&WT11[(k << 8) + gbase];
      v2f wlo, whi; wlo[0] = wv.x; wlo[1] = wv.y; whi[0] = wv.z; whi[1] = wv.w;
#pragma unroll
      for (int rr = 0; rr < 4; rr++) {
        const v2f hk = bc2(rl_f(h1reg[rr], k));
        aA[rr] += wlo * hk; aB[rr] += whi * hk;
      }
    }
#pragma unroll
    for (int rr = 0; rr < 4; rr++) {
      float4 gv; gv.x = aA[rr][0]; gv.y = aA[rr][1]; gv.z = aB[rr][0]; gv.w = aB[rr][1];
      *(float4*)&g_s[r0 + rr][gbase] = gv;
    }

#pragma unroll
    for (int rr = 0; rr < 4; rr++) {
      const int row = r0 + rr;
      const float gi = g_s[row][lane]       + bs4;
      const float gf = g_s[row][64 + lane]  + bs5;
      const float gg = g_s[row][128 + lane] + bs6;
      const float go = g_s[row][192 + lane] + bs7;
      float c1 = c1reg[rr];
      c1 = sigm(gf) * c1 + sigm(gi) * tanhf(gg);
      c1reg[rr] = c1;
      const float h1v = sigm(go) * tanhf(c1);
      h1reg[rr] = h1v;
      float pd = h1v * wdfv, pl = h1v * wlocv, ps = h1v * wscv;
#pragma unroll
      for (int off = 32; off > 0; off >>= 1) {
        pd += __shfl_down(pd, off, 64);
        pl += __shfl_down(pl, off, 64);
        ps += __shfl_down(ps, off, 64);
      }
      if (lane == 0) {
        dfL[row]  = 2.0f + softplusf(pd + bdf);
        locL[row] = pl + bloc;
        scL[row]  = softplusf(ps + bsc);
      }
    }

    if (lane < 4) {
      const int row = r0 + lane, rg = base + row;
      const float dfv = dfL[row], lv = locL[row], scv = scL[row];
      const float* Rp = RND + ((size_t)s * RTOT + rg) * 4;
      const float z = Rp[0];
      const float alpha = dfv * 0.5f;
      float gam;
      {
#pragma clang fp contract(off)
        const float d = alpha - 0.33333334f;
        const float c = 0.33333334f / sqrtf(d);
        float x = Rp[1];
        float v = 1.0f + x * c;
        bool ok = true;
        if (v <= 0.0f) { x = Rp[2]; v = 1.0f + x * c; ok = (v > 0.0f); }
        const float X = x * x;
        const float V = (v * v) * v;
        const float U = Rp[3];
        bool accept = false;
        if (ok) {
          if (!(U >= 1.0f - 0.0331f * (X * X))) accept = true;
          else if (!(logf(U) >= 0.5f * X + d * ((1.0f - V) + logf(V)))) accept = true;
        }
        if (accept) {
          gam = d * V;
        } else {
          u32 ks0, ks1, skg0, skg1, gk0, gk1;
          tf2x32(kl0, kl1, 0u, (u32)s, ks0, ks1);
          tf2x32(ks0, ks1, 0u, 1u, skg0, skg1);
          jx_subkey(skg0, skg1, RTOT, (u32)rg, gk0, gk1);
          gam = jax_gamma_one(gk0, gk1, alpha);
        }
      }
      const float y = (lv + scv * (z * sqrtf(dfv / (2.0f * gam)))) * tsr[row];
      yhat[(size_t)rg * TM1 + CTX + s] = y;
      prevs[row] = y;
    }
  }
}

// ---------------- kernel 6: median over 100 samples per (b,t) ----------------
__global__ void __launch_bounds__(256) median_kernel(
    const float* __restrict__ yhat, float* __restrict__ out)
{
  __shared__ float vals[4][100];
  const int wave = threadIdx.x >> 6, lane = threadIdx.x & 63;
  const int cell = blockIdx.x * 4 + wave;
  const int b = cell / TM1, t = cell - b * TM1;
  const float* basep = yhat + (size_t)b * NSAMP * TM1 + t;
  const float v1 = basep[(size_t)lane * TM1];
  vals[wave][lane] = v1;
  float v2 = 0.f;
  if (lane < 36) { v2 = basep[(size_t)(64 + lane) * TM1]; vals[wave][64 + lane] = v2; }
  __syncthreads();
  int cl1 = 0, ce1 = 0, cl2 = 0, ce2 = 0;
  for (int jj = 0; jj < 100; jj++) {
    const float w = vals[wave][jj];
    cl1 += (w < v1); ce1 += (w == v1);
    cl2 += (w < v2); ce2 += (w == v2);
  }
  if (cl1 <= 49 && 49 < cl1 + ce1) out[cell] = v1;
  if (lane < 36 && cl2 <= 49 && 49 < cl2 + ce2) out[cell] = v2;
}

// ---------------- launch ----------------
extern "C" void kernel_launch(void* const* d_in, const int* in_sizes, int n_in,
                              void* d_out, int out_size, void* d_ws, size_t ws_size,
                              hipStream_t stream) {
  (void)in_sizes; (void)n_in; (void)out_size; (void)ws_size;
  const float* X     = (const float*)d_in[0];
  const float* Wih0  = (const float*)d_in[2];
  const float* Whh0  = (const float*)d_in[3];
  const float* bih0  = (const float*)d_in[4];
  const float* bhh0  = (const float*)d_in[5];
  const float* Wih1  = (const float*)d_in[6];
  const float* Whh1  = (const float*)d_in[7];
  const float* bih1  = (const float*)d_in[8];
  const float* bhh1  = (const float*)d_in[9];
  const float* wdf   = (const float*)d_in[10];
  const float* bdf   = (const float*)d_in[11];
  const float* wloc  = (const float*)d_in[12];
  const float* bloc  = (const float*)d_in[13];
  const float* wsc   = (const float*)d_in[14];
  const float* bsc   = (const float*)d_in[15];
  const float* emb   = (const float*)d_in[16];

  float* wsf = (float*)d_ws;
  float* inp  = wsf + OFF_INP;
  float* ct   = wsf + OFF_CT;
  float* ts   = wsf + OFF_TS;
  float* lts  = wsf + OFF_LTS;
  float* dfp  = wsf + OFF_DF;
  float* locp = wsf + OFF_LOC;
  float* scp  = wsf + OFF_SC;
  float* h0f  = wsf + OFF_H0F;
  float* c0f  = wsf + OFF_C0F;
  float* h1f  = wsf + OFF_H1F;
  float* c1f  = wsf + OFF_C1F;
  float* yhat = wsf + OFF_YH;
  float* wtx  = wsf + OFF_WTX;
  float* wt00 = wsf + OFF_WT00;
  float* wt10 = wsf + OFF_WT10;
  float* wt11 = wsf + OFF_WT11;
  float* rnd  = wsf + OFF_RND;

  const u32 key0 = 0u, key1 = 42u;
  u32 kc0, kc1, kl0, kl1;
  jx_subkey(key0, key1, 2u, 0u, kc0, kc1);
  jx_subkey(key0, key1, 2u, 1u, kl0, kl1);
  u32 kz0, kz1, kg0, kg1;
  jx_subkey(kc0, kc1, 2u, 0u, kz0, kz1);
  jx_subkey(kc0, kc1, 2u, 1u, kg0, kg1);

  wtrans_kernel<<<208, 256, 0, stream>>>(Wih0, Whh0, Wih1, Whh1, wtx, wt00, wt10, wt11);
  rnd_dec_kernel<<<(NSTEP * RTOT) / 256, 256, 0, stream>>>(rnd, kl0, kl1);
  prep_kernel<<<NB, 256, 0, stream>>>(X, emb, inp, ct, ts, lts);
  ctx_lstm_kernel<<<NB, 256, 0, stream>>>(inp, wtx, wt00, wt10, wt11,
                                          bih0, bhh0, bih1, bhh1,
                                          wdf, bdf, wloc, bloc, wsc, bsc,
                                          dfp, locp, scp, h0f, c0f, h1f, c1f);
  ctx_sample_kernel<<<NCTXS / 256, 256, 0, stream>>>(dfp, locp, scp, ts, yhat, kz0, kz1, kg0, kg1);
  dec_persist_kernel<<<DBLOCKS, 256, 0, stream>>>(inp, ts, wtx, wt00, wt10, wt11,
                                                  bih0, bhh0, bih1, bhh1,
                                                  wdf, bdf, wloc, bloc, wsc, bsc,
                                                  h0f, c0f, h1f, c1f, ct, rnd, yhat, kl0, kl1);
  median_kernel<<<(NB * TM1) / 4, 256, 0, stream>>>(yhat, (float*)d_out);
}